// Round 3
// baseline (1307.338 us; speedup 1.0000x reference)
//
#include <hip/hip_runtime.h>
#include <hip/hip_bf16.h>
#include <math.h>

#define NBH 128      // B*H
#define LQ  4096     // L
#define SK  4096     // S
#define DH  64       // head dim
#define NS  45       // U = FACTOR*ceil(log(4096)) = 45
#define TOPSTRIDE 48
#define NCH 8        // key split chunks per bh
#define CK  512      // keys per chunk
#define NSUB 8       // subchunks of 64 keys

// ---------------- Kernel 1: M = max_k(QKs) - sum_k(QKs)/S ----------------
// one wave per 64 query rows; lane k holds K_sample row k in registers.
__global__ __launch_bounds__(256) void kernelM(const float* __restrict__ Q,
                                               const float* __restrict__ K,
                                               const int* __restrict__ sidx,
                                               float* __restrict__ M) {
    int wid  = (blockIdx.x << 2) | (threadIdx.x >> 6);   // 8192 waves
    int lane = threadIdx.x & 63;
    int bh   = wid >> 6;                 // 128
    int rowbase = (wid & 63) << 6;       // 64 rows per wave
    int k = lane < NS ? lane : NS - 1;
    const float* krow = K + ((size_t)bh * SK + sidx[k]) * DH;
    float ks[DH];
#pragma unroll
    for (int i = 0; i < 16; i++) {
        float4 v = *(const float4*)(krow + 4 * i);
        ks[4*i] = v.x; ks[4*i+1] = v.y; ks[4*i+2] = v.z; ks[4*i+3] = v.w;
    }
    bool act = lane < NS;
    const float* qbase = Q + ((size_t)bh * LQ + rowbase) * DH;
    for (int r = 0; r < 64; r++) {
        const float* q = qbase + r * DH;
        float dot = 0.f;
#pragma unroll
        for (int jj = 0; jj < 16; jj++) {
            float4 qv = *(const float4*)(q + 4 * jj);
            dot += ks[4*jj+0] * qv.x;
            dot += ks[4*jj+1] * qv.y;
            dot += ks[4*jj+2] * qv.z;
            dot += ks[4*jj+3] * qv.w;
        }
        float vmax = act ? dot : -INFINITY;
        float vsum = act ? dot : 0.f;
#pragma unroll
        for (int off = 32; off; off >>= 1) {
            vmax = fmaxf(vmax, __shfl_xor(vmax, off, 64));
            vsum += __shfl_xor(vsum, off, 64);
        }
        if (lane == 0)
            M[((size_t)bh << 12) + rowbase + r] = vmax - vsum * (1.0f / 4096.0f);
    }
}

// ---------------- Kernel 2: top-45 per bh ----------------
__global__ __launch_bounds__(256) void kernelTopK(const float* __restrict__ M,
                                                  int* __restrict__ top) {
    __shared__ float m[LQ];
    __shared__ float rv[256];
    __shared__ int   ri[256];
    int bh = blockIdx.x;
    for (int i = threadIdx.x; i < LQ; i += 256) m[i] = M[((size_t)bh << 12) + i];
    __syncthreads();
    for (int it = 0; it < NS; ++it) {
        float bv = -INFINITY; int bi = 0x7fffffff;
        for (int i = threadIdx.x; i < LQ; i += 256) {
            float v = m[i];
            if (v > bv) { bv = v; bi = i; }   // ascending scan keeps first on tie
        }
        rv[threadIdx.x] = bv; ri[threadIdx.x] = bi;
        __syncthreads();
        for (int s = 128; s; s >>= 1) {
            if (threadIdx.x < s) {
                float ov = rv[threadIdx.x + s]; int oi = ri[threadIdx.x + s];
                if (ov > rv[threadIdx.x] || (ov == rv[threadIdx.x] && oi < ri[threadIdx.x])) {
                    rv[threadIdx.x] = ov; ri[threadIdx.x] = oi;
                }
            }
            __syncthreads();
        }
        if (threadIdx.x == 0) { top[bh * TOPSTRIDE + it] = ri[0]; m[ri[0]] = -INFINITY; }
        __syncthreads();
    }
}

// ---------------- Kernel 3: split-K attention over selected queries + V column-sum ----------------
__global__ __launch_bounds__(256) void kernelAttn(const float* __restrict__ Q,
                                                  const float* __restrict__ K,
                                                  const float* __restrict__ V,
                                                  const int* __restrict__ top,
                                                  float* __restrict__ pm,
                                                  float* __restrict__ pl,
                                                  float* __restrict__ pacc,
                                                  float* __restrict__ vsum) {
    __shared__ float Qr[NS][DH];
    __shared__ float KT[DH][64];   // transposed key subchunk
    __shared__ float Vc[64][DH];
    __shared__ float sl[NS][64];
    __shared__ float vred[4][64];

    int bh = blockIdx.x >> 3;
    int c  = blockIdx.x & 7;
    int tid = threadIdx.x;
    int widx = tid >> 6, lane = tid & 63;

    for (int idx = tid; idx < NS * 16; idx += 256) {
        int u = idx >> 4, f4 = idx & 15;
        int row = top[bh * TOPSTRIDE + u];
        *(float4*)&Qr[u][f4 * 4] =
            *(const float4*)(Q + (((size_t)bh << 12) + row) * DH + f4 * 4);
    }
    float mreg[12], lreg[12], acc[12];
#pragma unroll
    for (int i = 0; i < 12; i++) { mreg[i] = -INFINITY; lreg[i] = 0.f; acc[i] = 0.f; }
    float vacc = 0.f;
    const size_t kbase = (((size_t)bh << 12) + (size_t)c * CK) * DH;
    __syncthreads();

    for (int sub = 0; sub < NSUB; ++sub) {
        // stage K^T and V: 64 rows x 16 float4
        for (int idx = tid; idx < 1024; idx += 256) {
            int r = idx >> 4, f4 = idx & 15;
            float4 kv = *(const float4*)(K + kbase + (size_t)(sub * 64 + r) * DH + f4 * 4);
            KT[f4*4+0][r] = kv.x; KT[f4*4+1][r] = kv.y;
            KT[f4*4+2][r] = kv.z; KT[f4*4+3][r] = kv.w;
            *(float4*)&Vc[r][f4 * 4] =
                *(const float4*)(V + kbase + (size_t)(sub * 64 + r) * DH + f4 * 4);
        }
        __syncthreads();
        // scores: wave w computes rows u = w, w+4, ...; lane = key j
#pragma unroll
        for (int kq = 0; kq < 12; kq++) {
            int u = widx + 4 * kq;
            if (u < NS) {
                float d0 = 0.f;
#pragma unroll
                for (int jj = 0; jj < 16; jj++) {
                    float4 qv = *(const float4*)&Qr[u][jj * 4];
                    d0 += qv.x * KT[jj*4+0][lane];
                    d0 += qv.y * KT[jj*4+1][lane];
                    d0 += qv.z * KT[jj*4+2][lane];
                    d0 += qv.w * KT[jj*4+3][lane];
                }
                sl[u][lane] = d0 * 0.125f;
            }
        }
        // V column partial sum (thread-local, reads staged Vc)
        {
            int col = lane, part = widx;
#pragma unroll
            for (int r = 0; r < 16; r++) vacc += Vc[part * 16 + r][col];
        }
        // online softmax + PV (wave-internal only; no barrier needed)
#pragma unroll
        for (int kq = 0; kq < 12; kq++) {
            int u = widx + 4 * kq;
            if (u < NS) {
                float sc = sl[u][lane];
                float mx = sc;
#pragma unroll
                for (int off = 32; off; off >>= 1) mx = fmaxf(mx, __shfl_xor(mx, off, 64));
                float mnew = fmaxf(mreg[kq], mx);
                float p = expf(sc - mnew);
                float rescale = expf(mreg[kq] - mnew);
                float ps = p;
#pragma unroll
                for (int off = 32; off; off >>= 1) ps += __shfl_xor(ps, off, 64);
                lreg[kq] = lreg[kq] * rescale + ps;
                mreg[kq] = mnew;
                sl[u][lane] = p;             // same-wave LDS round trip
                float a = acc[kq] * rescale;
#pragma unroll
                for (int j4 = 0; j4 < 16; j4++) {
                    float4 pv = *(const float4*)&sl[u][j4 * 4];
                    a += pv.x * Vc[j4*4+0][lane];
                    a += pv.y * Vc[j4*4+1][lane];
                    a += pv.z * Vc[j4*4+2][lane];
                    a += pv.w * Vc[j4*4+3][lane];
                }
                acc[kq] = a;
            }
        }
        __syncthreads();
    }
    // write partials
#pragma unroll
    for (int kq = 0; kq < 12; kq++) {
        int u = widx + 4 * kq;
        if (u < NS) {
            size_t pidx = ((size_t)bh * NCH + c) * TOPSTRIDE + u;
            if (lane == 0) { pm[pidx] = mreg[kq]; pl[pidx] = lreg[kq]; }
            pacc[pidx * DH + lane] = acc[kq];
        }
    }
    // V_sum reduce + atomic
    vred[widx][lane] = vacc;
    __syncthreads();
    if (widx == 0) {
        float t = vred[0][lane] + vred[1][lane] + vred[2][lane] + vred[3][lane];
        atomicAdd(vsum + bh * DH + lane, t);
    }
}

// ---------------- Kernel 4: broadcast V_sum into all output rows ----------------
__global__ __launch_bounds__(256) void kernelBroadcast(const float* __restrict__ vsum,
                                                       float4* __restrict__ out4) {
    size_t i = (size_t)blockIdx.x * 256 + threadIdx.x;   // 8388608 float4s
    int bh = (int)(i >> 16);
    int d4 = (int)(i & 15);
    out4[i] = *(const float4*)(vsum + bh * DH + d4 * 4);
}

// ---------------- Kernel 5: combine split-K partials, scatter into output ----------------
__global__ __launch_bounds__(256) void kernelCombine(const float* __restrict__ pm,
                                                     const float* __restrict__ pl,
                                                     const float* __restrict__ pacc,
                                                     const int* __restrict__ top,
                                                     float* __restrict__ out) {
    int g = (blockIdx.x << 2) | (threadIdx.x >> 6);  // one wave per (bh,u)
    int lane = threadIdx.x & 63;
    int bh = g / 45, u = g - bh * 45;
    float mc[NCH], lc[NCH];
    float mstar = -INFINITY;
#pragma unroll
    for (int c = 0; c < NCH; c++) {
        size_t pidx = ((size_t)bh * NCH + c) * TOPSTRIDE + u;
        mc[c] = pm[pidx]; lc[c] = pl[pidx];
        mstar = fmaxf(mstar, mc[c]);
    }
    float denom = 0.f, ctx = 0.f;
#pragma unroll
    for (int c = 0; c < NCH; c++) {
        size_t pidx = ((size_t)bh * NCH + c) * TOPSTRIDE + u;
        float w = expf(mc[c] - mstar);
        denom += lc[c] * w;
        ctx += w * pacc[pidx * DH + lane];
    }
    int row = top[bh * TOPSTRIDE + u];
    out[(((size_t)bh << 12) + row) * DH + lane] = ctx / denom;
}

extern "C" void kernel_launch(void* const* d_in, const int* in_sizes, int n_in,
                              void* d_out, int out_size, void* d_ws, size_t ws_size,
                              hipStream_t stream) {
    const float* Q = (const float*)d_in[0];
    const float* K = (const float*)d_in[1];
    const float* V = (const float*)d_in[2];
    const int* sidx = (const int*)d_in[3];
    float* out = (float*)d_out;

    float* ws = (float*)d_ws;
    float* wsM    = ws;                                  // 524288
    int*   wsTop  = (int*)(ws + 524288);                 // 6144
    float* wsVsum = ws + 524288 + 6144;                  // 8192
    float* wsPm   = wsVsum + 8192;                       // 49152
    float* wsPl   = wsPm + 49152;                        // 49152
    float* wsPacc = wsPl + 49152;                        // 3145728

    hipMemsetAsync(wsVsum, 0, NBH * DH * sizeof(float), stream);
    kernelM<<<2048, 256, 0, stream>>>(Q, K, sidx, wsM);
    kernelTopK<<<NBH, 256, 0, stream>>>(wsM, wsTop);
    kernelAttn<<<NBH * NCH, 256, 0, stream>>>(Q, K, V, wsTop, wsPm, wsPl, wsPacc, wsVsum);
    kernelBroadcast<<<32768, 256, 0, stream>>>(wsVsum, (float4*)out);
    kernelCombine<<<1440, 256, 0, stream>>>(wsPm, wsPl, wsPacc, wsTop, out);
}

// Round 4
// 767.356 us; speedup vs baseline: 1.7037x; 1.7037x over previous
//
#include <hip/hip_runtime.h>
#include <hip/hip_bf16.h>
#include <math.h>

#define NBH 128      // B*H
#define LQ  4096
#define SK  4096
#define DH  64
#define NS  45       // U
#define TOPSTRIDE 48
#define NCH 8        // key chunks per bh (per block)
#define CK  512      // keys per block-chunk; each of 4 waves owns 128 keys

typedef __attribute__((ext_vector_type(8))) short short8v;
typedef __attribute__((ext_vector_type(4))) short short4v;
typedef __attribute__((ext_vector_type(4))) float f32x4;

static __device__ __forceinline__ short f2b(float x) {
    union { __hip_bfloat16 h; short s; } u;
    u.h = __float2bfloat16(x);
    return u.s;
}
static __device__ __forceinline__ short8v cvt8(const float* p) {
    float4 a = *(const float4*)p, b = *(const float4*)(p + 4);
    short8v r;
    r[0]=f2b(a.x); r[1]=f2b(a.y); r[2]=f2b(a.z); r[3]=f2b(a.w);
    r[4]=f2b(b.x); r[5]=f2b(b.y); r[6]=f2b(b.z); r[7]=f2b(b.w);
    return r;
}
static __device__ __forceinline__ f32x4 mfma16(short4v a, short4v b, f32x4 c) {
#if __has_builtin(__builtin_amdgcn_mfma_f32_16x16x16bf16_1k)
    return __builtin_amdgcn_mfma_f32_16x16x16bf16_1k(a, b, c, 0, 0, 0);
#else
    asm volatile("v_mfma_f32_16x16x16_bf16 %0, %1, %2, %0" : "+v"(c) : "v"(a), "v"(b));
    return c;
#endif
}

// ---------------- Kernel 1: M = max_k(QKs) - sum_k(QKs)/S (unchanged) ----------------
__global__ __launch_bounds__(256) void kernelM(const float* __restrict__ Q,
                                               const float* __restrict__ K,
                                               const int* __restrict__ sidx,
                                               float* __restrict__ M) {
    int wid  = (blockIdx.x << 2) | (threadIdx.x >> 6);
    int lane = threadIdx.x & 63;
    int bh   = wid >> 6;
    int rowbase = (wid & 63) << 6;
    int k = lane < NS ? lane : NS - 1;
    const float* krow = K + ((size_t)bh * SK + sidx[k]) * DH;
    float ks[DH];
#pragma unroll
    for (int i = 0; i < 16; i++) {
        float4 v = *(const float4*)(krow + 4 * i);
        ks[4*i] = v.x; ks[4*i+1] = v.y; ks[4*i+2] = v.z; ks[4*i+3] = v.w;
    }
    bool act = lane < NS;
    const float* qbase = Q + ((size_t)bh * LQ + rowbase) * DH;
    for (int r = 0; r < 64; r++) {
        const float* q = qbase + r * DH;
        float dot = 0.f;
#pragma unroll
        for (int jj = 0; jj < 16; jj++) {
            float4 qv = *(const float4*)(q + 4 * jj);
            dot += ks[4*jj+0] * qv.x;
            dot += ks[4*jj+1] * qv.y;
            dot += ks[4*jj+2] * qv.z;
            dot += ks[4*jj+3] * qv.w;
        }
        float vmax = act ? dot : -INFINITY;
        float vsum = act ? dot : 0.f;
#pragma unroll
        for (int off = 32; off; off >>= 1) {
            vmax = fmaxf(vmax, __shfl_xor(vmax, off, 64));
            vsum += __shfl_xor(vsum, off, 64);
        }
        if (lane == 0)
            M[((size_t)bh << 12) + rowbase + r] = vmax - vsum * (1.0f / 4096.0f);
    }
}

// ---------------- Kernel 2: top-45 per bh (unchanged) ----------------
__global__ __launch_bounds__(256) void kernelTopK(const float* __restrict__ M,
                                                  int* __restrict__ top) {
    __shared__ float m[LQ];
    __shared__ float rv[256];
    __shared__ int   ri[256];
    int bh = blockIdx.x;
    for (int i = threadIdx.x; i < LQ; i += 256) m[i] = M[((size_t)bh << 12) + i];
    __syncthreads();
    for (int it = 0; it < NS; ++it) {
        float bv = -INFINITY; int bi = 0x7fffffff;
        for (int i = threadIdx.x; i < LQ; i += 256) {
            float v = m[i];
            if (v > bv) { bv = v; bi = i; }
        }
        rv[threadIdx.x] = bv; ri[threadIdx.x] = bi;
        __syncthreads();
        for (int s = 128; s; s >>= 1) {
            if (threadIdx.x < s) {
                float ov = rv[threadIdx.x + s]; int oi = ri[threadIdx.x + s];
                if (ov > rv[threadIdx.x] || (ov == rv[threadIdx.x] && oi < ri[threadIdx.x])) {
                    rv[threadIdx.x] = ov; ri[threadIdx.x] = oi;
                }
            }
            __syncthreads();
        }
        if (threadIdx.x == 0) { top[bh * TOPSTRIDE + it] = ri[0]; m[ri[0]] = -INFINITY; }
        __syncthreads();
    }
}

// ---------------- Kernel 3 (NEW): MFMA attention, no main-loop LDS ----------------
// block = (bh, chunk c of 512 keys); wave w owns 128 keys, 8 subs of 16.
// S^T = mfma_16x16x32(K, Q): D-frag holds P^T[key=4b+r][q=n] == PV A-frag layout.
__global__ __launch_bounds__(256) void kernelAttn2(const float* __restrict__ Q,
                                                   const float* __restrict__ K,
                                                   const float* __restrict__ V,
                                                   const int* __restrict__ top,
                                                   float* __restrict__ pm,
                                                   float* __restrict__ pl,
                                                   float* __restrict__ pacc,
                                                   float* __restrict__ vsum) {
    __shared__ float lm[4][48];
    __shared__ float ll[4][48];
    __shared__ __attribute__((aligned(16))) float ob[48][68];

    const int bh = blockIdx.x >> 3, c = blockIdx.x & 7;
    const int tid = threadIdx.x, w = tid >> 6, l = tid & 63;
    const int b = l >> 4, n = l & 15;
    const int kwavebase = c * CK + w * 128;   // within bh
    const size_t bhoff = ((size_t)bh << 12) * DH;

    // Q fragments (register-resident, bf16): qf[qt][t] = Q[top[qt*16+n]][32t+8b .. +8]
    const int* topb = top + bh * TOPSTRIDE;
    short8v qf[3][2];
#pragma unroll
    for (int qt = 0; qt < 3; qt++) {
        int q = qt * 16 + n;
        int row = topb[q < NS ? q : NS - 1];
        const float* qp = Q + bhoff + (size_t)row * DH;
#pragma unroll
        for (int t = 0; t < 2; t++) qf[qt][t] = cvt8(qp + 32 * t + 8 * b);
    }

    f32x4 o[3][4];
    float m_run[3], l_run[3], vacc[4];
#pragma unroll
    for (int qt = 0; qt < 3; qt++) {
        m_run[qt] = -INFINITY; l_run[qt] = 0.f;
#pragma unroll
        for (int dt = 0; dt < 4; dt++) { o[qt][dt][0]=0.f; o[qt][dt][1]=0.f; o[qt][dt][2]=0.f; o[qt][dt][3]=0.f; }
    }
#pragma unroll
    for (int dt = 0; dt < 4; dt++) vacc[dt] = 0.f;

    for (int s = 0; s < 8; ++s) {
        // K A-frags: lane(b,n): K[kb + s*16 + n][8b + 32t ..+8]
        const float* kp = K + bhoff + (size_t)(kwavebase + s * 16 + n) * DH;
        short8v ka0 = cvt8(kp + 8 * b);
        short8v ka1 = cvt8(kp + 32 + 8 * b);
        // V B-frags: lane(b,n): V[kb + s*16 + 4b + j][dt*16 + n]
        const float* vp = V + bhoff + (size_t)(kwavebase + s * 16 + 4 * b) * DH;
        short4v vb[4];
#pragma unroll
        for (int dt = 0; dt < 4; dt++) {
            float v0 = vp[0 * DH + dt * 16 + n];
            float v1 = vp[1 * DH + dt * 16 + n];
            float v2 = vp[2 * DH + dt * 16 + n];
            float v3 = vp[3 * DH + dt * 16 + n];
            vacc[dt] += (v0 + v1) + (v2 + v3);
            short4v vv; vv[0]=f2b(v0); vv[1]=f2b(v1); vv[2]=f2b(v2); vv[3]=f2b(v3);
            vb[dt] = vv;
        }
        // S^T tiles
        f32x4 st[3];
        float mnew[3];
        bool need = false;
#pragma unroll
        for (int qt = 0; qt < 3; qt++) {
            f32x4 acc0 = {0.f, 0.f, 0.f, 0.f};
            acc0 = __builtin_amdgcn_mfma_f32_16x16x32_bf16(ka0, qf[qt][0], acc0, 0, 0, 0);
            acc0 = __builtin_amdgcn_mfma_f32_16x16x32_bf16(ka1, qf[qt][1], acc0, 0, 0, 0);
            acc0 = acc0 * 0.125f;                          // 1/sqrt(64)
            st[qt] = acc0;
            float tm = fmaxf(fmaxf(acc0[0], acc0[1]), fmaxf(acc0[2], acc0[3]));
            tm = fmaxf(tm, __shfl_xor(tm, 16, 64));
            tm = fmaxf(tm, __shfl_xor(tm, 32, 64));
            mnew[qt] = fmaxf(m_run[qt], tm);
            need = need || (mnew[qt] > m_run[qt]);
        }
        if (__any(need)) {
            float rl[3];
#pragma unroll
            for (int qt = 0; qt < 3; qt++) {
                rl[qt] = __expf(m_run[qt] - mnew[qt]);
                l_run[qt] *= rl[qt];
            }
#pragma unroll
            for (int qt = 0; qt < 3; qt++) {
#pragma unroll
                for (int rr = 0; rr < 4; rr++) {
                    float rs = __shfl(rl[qt], 20 * b + rr, 64);
#pragma unroll
                    for (int dt = 0; dt < 4; dt++) o[qt][dt][rr] *= rs;
                }
            }
        }
#pragma unroll
        for (int qt = 0; qt < 3; qt++) {
            float p0 = __expf(st[qt][0] - mnew[qt]);
            float p1 = __expf(st[qt][1] - mnew[qt]);
            float p2 = __expf(st[qt][2] - mnew[qt]);
            float p3 = __expf(st[qt][3] - mnew[qt]);
            float ps = (p0 + p1) + (p2 + p3);
            ps += __shfl_xor(ps, 16, 64);
            ps += __shfl_xor(ps, 32, 64);
            l_run[qt] += ps;
            m_run[qt] = mnew[qt];
            short4v pa; pa[0]=f2b(p0); pa[1]=f2b(p1); pa[2]=f2b(p2); pa[3]=f2b(p3);
#pragma unroll
            for (int dt = 0; dt < 4; dt++) o[qt][dt] = mfma16(pa, vb[dt], o[qt][dt]);
        }
    }

    // ---- block combine (4 waves -> one partial per block) ----
    if (b == 0) {
#pragma unroll
        for (int qt = 0; qt < 3; qt++) lm[w][qt * 16 + n] = m_run[qt];
    }
    __syncthreads();
    float wf[3];
    {
        float mblk[3], lw[3];
#pragma unroll
        for (int qt = 0; qt < 3; qt++) {
            int q = qt * 16 + n;
            mblk[qt] = fmaxf(fmaxf(lm[0][q], lm[1][q]), fmaxf(lm[2][q], lm[3][q]));
            wf[qt] = __expf(m_run[qt] - mblk[qt]);
            lw[qt] = l_run[qt] * wf[qt];
        }
        if (b == 0) {
#pragma unroll
            for (int qt = 0; qt < 3; qt++) ll[w][qt * 16 + n] = lw[qt];
        }
        if (w == 0 && b == 0) {
#pragma unroll
            for (int qt = 0; qt < 3; qt++) {
                int q = qt * 16 + n;
                if (q < NS) pm[(size_t)(bh * NCH + c) * TOPSTRIDE + q] = mblk[qt];
            }
        }
    }
    float wsh[3][4];
#pragma unroll
    for (int qt = 0; qt < 3; qt++)
#pragma unroll
        for (int rr = 0; rr < 4; rr++) wsh[qt][rr] = __shfl(wf[qt], 20 * b + rr, 64);

    for (int ww = 0; ww < 4; ++ww) {
        if (w == ww) {
#pragma unroll
            for (int qt = 0; qt < 3; qt++)
#pragma unroll
                for (int dt = 0; dt < 4; dt++)
#pragma unroll
                    for (int rr = 0; rr < 4; rr++) {
                        int q = qt * 16 + 4 * b + rr, d = dt * 16 + n;
                        float val = o[qt][dt][rr] * wsh[qt][rr];
                        if (ww == 0) ob[q][d] = val; else ob[q][d] += val;
                    }
        }
        __syncthreads();
    }
    // final pl + pacc write
    if (w == 0 && b == 0) {
#pragma unroll
        for (int qt = 0; qt < 3; qt++) {
            int q = qt * 16 + n;
            if (q < NS)
                pl[(size_t)(bh * NCH + c) * TOPSTRIDE + q] =
                    ((ll[0][q] + ll[1][q]) + (ll[2][q] + ll[3][q]));
        }
    }
    for (int i = tid; i < NS * 16; i += 256) {
        int q = i >> 4, f4 = i & 15;
        float4 v = *(const float4*)&ob[q][f4 * 4];
        *(float4*)&pacc[((size_t)(bh * NCH + c) * TOPSTRIDE + q) * DH + f4 * 4] = v;
    }
    // V column-sum
#pragma unroll
    for (int dt = 0; dt < 4; dt++) {
        float t = vacc[dt];
        t += __shfl_xor(t, 16, 64);
        t += __shfl_xor(t, 32, 64);
        if (b == 0) atomicAdd(vsum + bh * DH + dt * 16 + n, t);
    }
}

// ---------------- Kernel 4: broadcast V_sum (unchanged) ----------------
__global__ __launch_bounds__(256) void kernelBroadcast(const float* __restrict__ vsum,
                                                       float4* __restrict__ out4) {
    size_t i = (size_t)blockIdx.x * 256 + threadIdx.x;
    int bh = (int)(i >> 16);
    int d4 = (int)(i & 15);
    out4[i] = *(const float4*)(vsum + bh * DH + d4 * 4);
}

// ---------------- Kernel 5: combine split-K partials (unchanged) ----------------
__global__ __launch_bounds__(256) void kernelCombine(const float* __restrict__ pm,
                                                     const float* __restrict__ pl,
                                                     const float* __restrict__ pacc,
                                                     const int* __restrict__ top,
                                                     float* __restrict__ out) {
    int g = (blockIdx.x << 2) | (threadIdx.x >> 6);
    int lane = threadIdx.x & 63;
    int bh = g / 45, u = g - bh * 45;
    float mc[NCH], lc[NCH];
    float mstar = -INFINITY;
#pragma unroll
    for (int c = 0; c < NCH; c++) {
        size_t pidx = ((size_t)bh * NCH + c) * TOPSTRIDE + u;
        mc[c] = pm[pidx]; lc[c] = pl[pidx];
        mstar = fmaxf(mstar, mc[c]);
    }
    float denom = 0.f, ctx = 0.f;
#pragma unroll
    for (int c = 0; c < NCH; c++) {
        size_t pidx = ((size_t)bh * NCH + c) * TOPSTRIDE + u;
        float wgt = __expf(mc[c] - mstar);
        denom += lc[c] * wgt;
        ctx += wgt * pacc[pidx * DH + lane];
    }
    int row = top[bh * TOPSTRIDE + u];
    out[(((size_t)bh << 12) + row) * DH + lane] = ctx / denom;
}

extern "C" void kernel_launch(void* const* d_in, const int* in_sizes, int n_in,
                              void* d_out, int out_size, void* d_ws, size_t ws_size,
                              hipStream_t stream) {
    const float* Q = (const float*)d_in[0];
    const float* K = (const float*)d_in[1];
    const float* V = (const float*)d_in[2];
    const int* sidx = (const int*)d_in[3];
    float* out = (float*)d_out;

    float* ws = (float*)d_ws;
    float* wsM    = ws;                                  // 524288
    int*   wsTop  = (int*)(ws + 524288);                 // 6144
    float* wsVsum = ws + 524288 + 6144;                  // 8192
    float* wsPm   = wsVsum + 8192;                       // 49152
    float* wsPl   = wsPm + 49152;                        // 49152
    float* wsPacc = wsPl + 49152;                        // 3145728

    hipMemsetAsync(wsVsum, 0, NBH * DH * sizeof(float), stream);
    kernelM<<<2048, 256, 0, stream>>>(Q, K, sidx, wsM);
    kernelTopK<<<NBH, 256, 0, stream>>>(wsM, wsTop);
    kernelAttn2<<<NBH * NCH, 256, 0, stream>>>(Q, K, V, wsTop, wsPm, wsPl, wsPacc, wsVsum);
    kernelBroadcast<<<32768, 256, 0, stream>>>(wsVsum, (float4*)out);
    kernelCombine<<<1440, 256, 0, stream>>>(wsPm, wsPl, wsPacc, wsTop, out);
}

// Round 7
// 541.023 us; speedup vs baseline: 2.4164x; 1.4183x over previous
//
#include <hip/hip_runtime.h>
#include <hip/hip_bf16.h>
#include <math.h>

#define NBH 128      // B*H
#define LQ  4096
#define SK  4096
#define DH  64
#define NS  45       // U
#define TOPSTRIDE 48
#define NCH 8        // key chunks per bh (per block)
#define CK  512      // keys per block-chunk; each of 4 waves owns 128 keys

typedef __attribute__((ext_vector_type(8))) short short8v;
typedef __attribute__((ext_vector_type(4))) short short4v;
typedef __attribute__((ext_vector_type(4))) float f32x4;

static __device__ __forceinline__ short f2b(float x) {
    union { __hip_bfloat16 h; short s; } u;
    u.h = __float2bfloat16(x);
    return u.s;
}
static __device__ __forceinline__ short8v cvt8(const float* p) {
    float4 a = *(const float4*)p, b = *(const float4*)(p + 4);
    short8v r;
    r[0]=f2b(a.x); r[1]=f2b(a.y); r[2]=f2b(a.z); r[3]=f2b(a.w);
    r[4]=f2b(b.x); r[5]=f2b(b.y); r[6]=f2b(b.z); r[7]=f2b(b.w);
    return r;
}
static __device__ __forceinline__ f32x4 mfma16(short4v a, short4v b, f32x4 c) {
#if __has_builtin(__builtin_amdgcn_mfma_f32_16x16x16bf16_1k)
    return __builtin_amdgcn_mfma_f32_16x16x16bf16_1k(a, b, c, 0, 0, 0);
#else
    asm volatile("v_mfma_f32_16x16x16_bf16 %0, %1, %2, %0" : "+v"(c) : "v"(a), "v"(b));
    return c;
#endif
}

// ---------------- Kernel 1: lane-per-query M-score ----------------
// block: 256 queries of one bh; K_sample staged in LDS, broadcast reads.
// No cross-lane ops; 4-way ILP in the dot; fp32 throughout (selection-exact).
__global__ __launch_bounds__(256) void kernelM(const float* __restrict__ Q,
                                               const float* __restrict__ K,
                                               const int* __restrict__ sidx,
                                               float* __restrict__ M) {
    __shared__ __attribute__((aligned(16))) float Ks[NS][DH];   // 11.5 KB
    const int bh = blockIdx.x >> 4;            // 16 blocks per bh
    const int qb = (blockIdx.x & 15) << 8;     // 256 queries per block
    for (int i = threadIdx.x; i < NS * 16; i += 256) {
        int k = i >> 4, f4 = i & 15;
        *(float4*)&Ks[k][f4 * 4] =
            *(const float4*)(K + ((size_t)bh * SK + sidx[k]) * DH + f4 * 4);
    }
    __syncthreads();
    const int q = qb + threadIdx.x;
    const float* qp = Q + (((size_t)bh << 12) + q) * DH;
    float qr[DH];
#pragma unroll
    for (int i = 0; i < 16; i++) {
        float4 v = *(const float4*)(qp + 4 * i);
        qr[4*i] = v.x; qr[4*i+1] = v.y; qr[4*i+2] = v.z; qr[4*i+3] = v.w;
    }
    float vmax = -INFINITY, vsum = 0.f;
#pragma unroll 3
    for (int k = 0; k < NS; k++) {
        float d0 = 0.f, d1 = 0.f, d2 = 0.f, d3 = 0.f;
#pragma unroll
        for (int j = 0; j < 16; j++) {
            float4 kv = *(const float4*)&Ks[k][4 * j];
            d0 += qr[4*j+0] * kv.x;
            d1 += qr[4*j+1] * kv.y;
            d2 += qr[4*j+2] * kv.z;
            d3 += qr[4*j+3] * kv.w;
        }
        float dot = (d0 + d1) + (d2 + d3);
        vmax = fmaxf(vmax, dot);
        vsum += dot;
    }
    M[((size_t)bh << 12) + q] = vmax - vsum * (1.0f / 4096.0f);
}

// ---------------- Kernel 2: top-45 per bh (unchanged) ----------------
__global__ __launch_bounds__(256) void kernelTopK(const float* __restrict__ M,
                                                  int* __restrict__ top) {
    __shared__ float m[LQ];
    __shared__ float rv[256];
    __shared__ int   ri[256];
    int bh = blockIdx.x;
    for (int i = threadIdx.x; i < LQ; i += 256) m[i] = M[((size_t)bh << 12) + i];
    __syncthreads();
    for (int it = 0; it < NS; ++it) {
        float bv = -INFINITY; int bi = 0x7fffffff;
        for (int i = threadIdx.x; i < LQ; i += 256) {
            float v = m[i];
            if (v > bv) { bv = v; bi = i; }
        }
        rv[threadIdx.x] = bv; ri[threadIdx.x] = bi;
        __syncthreads();
        for (int s = 128; s; s >>= 1) {
            if (threadIdx.x < s) {
                float ov = rv[threadIdx.x + s]; int oi = ri[threadIdx.x + s];
                if (ov > rv[threadIdx.x] || (ov == rv[threadIdx.x] && oi < ri[threadIdx.x])) {
                    rv[threadIdx.x] = ov; ri[threadIdx.x] = oi;
                }
            }
            __syncthreads();
        }
        if (threadIdx.x == 0) { top[bh * TOPSTRIDE + it] = ri[0]; m[ri[0]] = -INFINITY; }
        __syncthreads();
    }
}

// ---------------- Kernel 3: MFMA attention (unchanged) ----------------
__global__ __launch_bounds__(256) void kernelAttn2(const float* __restrict__ Q,
                                                   const float* __restrict__ K,
                                                   const float* __restrict__ V,
                                                   const int* __restrict__ top,
                                                   float* __restrict__ pm,
                                                   float* __restrict__ pl,
                                                   float* __restrict__ pacc,
                                                   float* __restrict__ vsum) {
    __shared__ float lm[4][48];
    __shared__ float ll[4][48];
    __shared__ __attribute__((aligned(16))) float ob[48][68];

    const int bh = blockIdx.x >> 3, c = blockIdx.x & 7;
    const int tid = threadIdx.x, w = tid >> 6, l = tid & 63;
    const int b = l >> 4, n = l & 15;
    const int kwavebase = c * CK + w * 128;
    const size_t bhoff = ((size_t)bh << 12) * DH;

    const int* topb = top + bh * TOPSTRIDE;
    short8v qf[3][2];
#pragma unroll
    for (int qt = 0; qt < 3; qt++) {
        int q = qt * 16 + n;
        int row = topb[q < NS ? q : NS - 1];
        const float* qp = Q + bhoff + (size_t)row * DH;
#pragma unroll
        for (int t = 0; t < 2; t++) qf[qt][t] = cvt8(qp + 32 * t + 8 * b);
    }

    f32x4 o[3][4];
    float m_run[3], l_run[3], vacc[4];
#pragma unroll
    for (int qt = 0; qt < 3; qt++) {
        m_run[qt] = -INFINITY; l_run[qt] = 0.f;
#pragma unroll
        for (int dt = 0; dt < 4; dt++) { o[qt][dt][0]=0.f; o[qt][dt][1]=0.f; o[qt][dt][2]=0.f; o[qt][dt][3]=0.f; }
    }
#pragma unroll
    for (int dt = 0; dt < 4; dt++) vacc[dt] = 0.f;

    for (int s = 0; s < 8; ++s) {
        const float* kp = K + bhoff + (size_t)(kwavebase + s * 16 + n) * DH;
        short8v ka0 = cvt8(kp + 8 * b);
        short8v ka1 = cvt8(kp + 32 + 8 * b);
        const float* vp = V + bhoff + (size_t)(kwavebase + s * 16 + 4 * b) * DH;
        short4v vb[4];
#pragma unroll
        for (int dt = 0; dt < 4; dt++) {
            float v0 = vp[0 * DH + dt * 16 + n];
            float v1 = vp[1 * DH + dt * 16 + n];
            float v2 = vp[2 * DH + dt * 16 + n];
            float v3 = vp[3 * DH + dt * 16 + n];
            vacc[dt] += (v0 + v1) + (v2 + v3);
            short4v vv; vv[0]=f2b(v0); vv[1]=f2b(v1); vv[2]=f2b(v2); vv[3]=f2b(v3);
            vb[dt] = vv;
        }
        f32x4 st[3];
        float mnew[3];
        bool need = false;
#pragma unroll
        for (int qt = 0; qt < 3; qt++) {
            f32x4 acc0 = {0.f, 0.f, 0.f, 0.f};
            acc0 = __builtin_amdgcn_mfma_f32_16x16x32_bf16(ka0, qf[qt][0], acc0, 0, 0, 0);
            acc0 = __builtin_amdgcn_mfma_f32_16x16x32_bf16(ka1, qf[qt][1], acc0, 0, 0, 0);
            acc0 = acc0 * 0.125f;
            st[qt] = acc0;
            float tm = fmaxf(fmaxf(acc0[0], acc0[1]), fmaxf(acc0[2], acc0[3]));
            tm = fmaxf(tm, __shfl_xor(tm, 16, 64));
            tm = fmaxf(tm, __shfl_xor(tm, 32, 64));
            mnew[qt] = fmaxf(m_run[qt], tm);
            need = need || (mnew[qt] > m_run[qt]);
        }
        if (__any(need)) {
            float rl[3];
#pragma unroll
            for (int qt = 0; qt < 3; qt++) {
                rl[qt] = __expf(m_run[qt] - mnew[qt]);
                l_run[qt] *= rl[qt];
            }
#pragma unroll
            for (int qt = 0; qt < 3; qt++) {
#pragma unroll
                for (int rr = 0; rr < 4; rr++) {
                    float rs = __shfl(rl[qt], 20 * b + rr, 64);
#pragma unroll
                    for (int dt = 0; dt < 4; dt++) o[qt][dt][rr] *= rs;
                }
            }
        }
#pragma unroll
        for (int qt = 0; qt < 3; qt++) {
            float p0 = __expf(st[qt][0] - mnew[qt]);
            float p1 = __expf(st[qt][1] - mnew[qt]);
            float p2 = __expf(st[qt][2] - mnew[qt]);
            float p3 = __expf(st[qt][3] - mnew[qt]);
            float ps = (p0 + p1) + (p2 + p3);
            ps += __shfl_xor(ps, 16, 64);
            ps += __shfl_xor(ps, 32, 64);
            l_run[qt] += ps;
            m_run[qt] = mnew[qt];
            short4v pa; pa[0]=f2b(p0); pa[1]=f2b(p1); pa[2]=f2b(p2); pa[3]=f2b(p3);
#pragma unroll
            for (int dt = 0; dt < 4; dt++) o[qt][dt] = mfma16(pa, vb[dt], o[qt][dt]);
        }
    }

    if (b == 0) {
#pragma unroll
        for (int qt = 0; qt < 3; qt++) lm[w][qt * 16 + n] = m_run[qt];
    }
    __syncthreads();
    float wf[3];
    {
        float mblk[3], lw[3];
#pragma unroll
        for (int qt = 0; qt < 3; qt++) {
            int q = qt * 16 + n;
            mblk[qt] = fmaxf(fmaxf(lm[0][q], lm[1][q]), fmaxf(lm[2][q], lm[3][q]));
            wf[qt] = __expf(m_run[qt] - mblk[qt]);
            lw[qt] = l_run[qt] * wf[qt];
        }
        if (b == 0) {
#pragma unroll
            for (int qt = 0; qt < 3; qt++) ll[w][qt * 16 + n] = lw[qt];
        }
        if (w == 0 && b == 0) {
#pragma unroll
            for (int qt = 0; qt < 3; qt++) {
                int q = qt * 16 + n;
                if (q < NS) pm[(size_t)(bh * NCH + c) * TOPSTRIDE + q] = mblk[qt];
            }
        }
    }
    float wsh[3][4];
#pragma unroll
    for (int qt = 0; qt < 3; qt++)
#pragma unroll
        for (int rr = 0; rr < 4; rr++) wsh[qt][rr] = __shfl(wf[qt], 20 * b + rr, 64);

    for (int ww = 0; ww < 4; ++ww) {
        if (w == ww) {
#pragma unroll
            for (int qt = 0; qt < 3; qt++)
#pragma unroll
                for (int dt = 0; dt < 4; dt++)
#pragma unroll
                    for (int rr = 0; rr < 4; rr++) {
                        int q = qt * 16 + 4 * b + rr, d = dt * 16 + n;
                        float val = o[qt][dt][rr] * wsh[qt][rr];
                        if (ww == 0) ob[q][d] = val; else ob[q][d] += val;
                    }
        }
        __syncthreads();
    }
    if (w == 0 && b == 0) {
#pragma unroll
        for (int qt = 0; qt < 3; qt++) {
            int q = qt * 16 + n;
            if (q < NS)
                pl[(size_t)(bh * NCH + c) * TOPSTRIDE + q] =
                    ((ll[0][q] + ll[1][q]) + (ll[2][q] + ll[3][q]));
        }
    }
    for (int i = tid; i < NS * 16; i += 256) {
        int q = i >> 4, f4 = i & 15;
        float4 v = *(const float4*)&ob[q][f4 * 4];
        *(float4*)&pacc[((size_t)(bh * NCH + c) * TOPSTRIDE + q) * DH + f4 * 4] = v;
    }
#pragma unroll
    for (int dt = 0; dt < 4; dt++) {
        float t = vacc[dt];
        t += __shfl_xor(t, 16, 64);
        t += __shfl_xor(t, 32, 64);
        if (b == 0) atomicAdd(vsum + bh * DH + dt * 16 + n, t);
    }
}

// ---------------- Kernel 4: broadcast V_sum (unchanged) ----------------
__global__ __launch_bounds__(256) void kernelBroadcast(const float* __restrict__ vsum,
                                                       float4* __restrict__ out4) {
    size_t i = (size_t)blockIdx.x * 256 + threadIdx.x;
    int bh = (int)(i >> 16);
    int d4 = (int)(i & 15);
    out4[i] = *(const float4*)(vsum + bh * DH + d4 * 4);
}

// ---------------- Kernel 5: combine split-K partials (unchanged) ----------------
__global__ __launch_bounds__(256) void kernelCombine(const float* __restrict__ pm,
                                                     const float* __restrict__ pl,
                                                     const float* __restrict__ pacc,
                                                     const int* __restrict__ top,
                                                     float* __restrict__ out) {
    int g = (blockIdx.x << 2) | (threadIdx.x >> 6);
    int lane = threadIdx.x & 63;
    int bh = g / 45, u = g - bh * 45;
    float mc[NCH], lc[NCH];
    float mstar = -INFINITY;
#pragma unroll
    for (int c = 0; c < NCH; c++) {
        size_t pidx = ((size_t)bh * NCH + c) * TOPSTRIDE + u;
        mc[c] = pm[pidx]; lc[c] = pl[pidx];
        mstar = fmaxf(mstar, mc[c]);
    }
    float denom = 0.f, ctx = 0.f;
#pragma unroll
    for (int c = 0; c < NCH; c++) {
        size_t pidx = ((size_t)bh * NCH + c) * TOPSTRIDE + u;
        float wgt = __expf(mc[c] - mstar);
        denom += lc[c] * wgt;
        ctx += wgt * pacc[pidx * DH + lane];
    }
    int row = top[bh * TOPSTRIDE + u];
    out[(((size_t)bh << 12) + row) * DH + lane] = ctx / denom;
}

extern "C" void kernel_launch(void* const* d_in, const int* in_sizes, int n_in,
                              void* d_out, int out_size, void* d_ws, size_t ws_size,
                              hipStream_t stream) {
    const float* Q = (const float*)d_in[0];
    const float* K = (const float*)d_in[1];
    const float* V = (const float*)d_in[2];
    const int* sidx = (const int*)d_in[3];
    float* out = (float*)d_out;

    float* ws = (float*)d_ws;
    float* wsM    = ws;                                  // 524288
    int*   wsTop  = (int*)(ws + 524288);                 // 6144
    float* wsVsum = ws + 524288 + 6144;                  // 8192
    float* wsPm   = wsVsum + 8192;                       // 49152
    float* wsPl   = wsPm + 49152;                        // 49152
    float* wsPacc = wsPl + 49152;                        // 3145728

    hipMemsetAsync(wsVsum, 0, NBH * DH * sizeof(float), stream);
    kernelM<<<NBH * 16, 256, 0, stream>>>(Q, K, sidx, wsM);
    kernelTopK<<<NBH, 256, 0, stream>>>(wsM, wsTop);
    kernelAttn2<<<NBH * NCH, 256, 0, stream>>>(Q, K, V, wsTop, wsPm, wsPl, wsPacc, wsVsum);
    kernelBroadcast<<<32768, 256, 0, stream>>>(wsVsum, (float4*)out);
    kernelCombine<<<1440, 256, 0, stream>>>(wsPm, wsPl, wsPacc, wsTop, out);
}